// Round 11
// baseline (41541.742 us; speedup 1.0000x reference)
//
#include <hip/hip_runtime.h>

#define SEQ 32768
#define ISZ 256
#define HSZ 512
#define OSZ 256
#define GWG 8            // 8 WGs (64 rows each)
#define RTHREADS 576     // 8 compute waves + 1 P-stager wave
#define SENT 0x7FAAAAAAu // NaN sentinel: h = tanh(finite) is never NaN

typedef _Float16 half2_t __attribute__((ext_vector_type(2)));

#if defined(__has_builtin)
#if __has_builtin(__builtin_amdgcn_fdot2)
#define HAVE_FDOT2 1
#endif
#endif

__device__ __forceinline__ float dot2f(half2_t a, half2_t b, float c) {
#ifdef HAVE_FDOT2
  return __builtin_amdgcn_fdot2(a, b, c, false);   // v_dot2_f32_f16
#else
  return fmaf((float)a.x, (float)b.x, fmaf((float)a.y, (float)b.y, c));
#endif
}
__device__ __forceinline__ half2_t bch2(unsigned u) {
  return __builtin_bit_cast(half2_t, u);
}
__device__ __forceinline__ unsigned pkrtz_u(float x, float y) {
  return __builtin_bit_cast(unsigned, __builtin_amdgcn_cvt_pkrtz(x, y));
}

// ---------------------------------------------------------------------------
// Generic tiled GEMM:  C[M,N] = A[M,K] @ W[N,K]^T + bias[N]
// ---------------------------------------------------------------------------
__global__ __launch_bounds__(256) void gemm_bt_bias(
    const float* __restrict__ A, const float* __restrict__ W,
    const float* __restrict__ bias, float* __restrict__ C,
    int M, int N, int K)
{
  __shared__ float As[32][68];
  __shared__ float Bs[32][68];
  const int tx = threadIdx.x;
  const int tn = tx & 15, tm = tx >> 4;
  const int m0 = blockIdx.x * 64, n0 = blockIdx.y * 64;
  const int kl = tx & 31;
  const int rl = tx >> 5;
  float acc[4][4] = {};

  for (int kt = 0; kt < K; kt += 32) {
#pragma unroll
    for (int i = 0; i < 8; ++i) {
      int m = rl + i * 8;
      As[kl][m] = A[(size_t)(m0 + m) * K + kt + kl];
      Bs[kl][m] = W[(size_t)(n0 + m) * K + kt + kl];
    }
    __syncthreads();
#pragma unroll
    for (int k = 0; k < 32; ++k) {
      float a[4], b[4];
#pragma unroll
      for (int i = 0; i < 4; ++i) a[i] = As[k][tm * 4 + i];
#pragma unroll
      for (int j = 0; j < 4; ++j) b[j] = Bs[k][tn * 4 + j];
#pragma unroll
      for (int i = 0; i < 4; ++i)
#pragma unroll
        for (int j = 0; j < 4; ++j)
          acc[i][j] = fmaf(a[i], b[j], acc[i][j]);
    }
    __syncthreads();
  }
#pragma unroll
  for (int i = 0; i < 4; ++i) {
    int m = m0 + tm * 4 + i;
#pragma unroll
    for (int j = 0; j < 4; ++j) {
      int n = n0 + tn * 4 + j;
      C[(size_t)m * N + n] = acc[i][j] + bias[n];
    }
  }
}

// 2-deep pipelined sentinel poll: two loads in flight, alternating vmcnt(1)
// waits -> detection lag ~1 RT. Callers must have at most the publish store
// outstanding at entry (its ack drain overlaps fabric visibility anyway).
__device__ __forceinline__ float poll_sent(const float* p, unsigned sent) {
  float a, b;
  asm volatile(
      "s_waitcnt vmcnt(0)\n\t"
      "global_load_dword %0, %2, off sc0 sc1\n\t"
      "global_load_dword %1, %2, off sc0 sc1\n"
      "1:\n\t"
      "s_waitcnt vmcnt(1)\n\t"
      "v_cmp_eq_u32 vcc, %3, %0\n\t"
      "s_cbranch_vccz 3f\n\t"
      "global_load_dword %0, %2, off sc0 sc1\n\t"
      "s_waitcnt vmcnt(1)\n\t"
      "v_cmp_eq_u32 vcc, %3, %1\n\t"
      "s_cbranch_vccz 2f\n\t"
      "global_load_dword %1, %2, off sc0 sc1\n\t"
      "s_branch 1b\n"
      "2:\n\t"
      "v_mov_b32 %0, %1\n"
      "3:\n\t"
      "s_waitcnt vmcnt(0)"
      : "=&v"(a), "=&v"(b)
      : "v"(p), "v"(sent)
      : "memory", "vcc");
  return a;
}

// ---------------------------------------------------------------------------
// Persistent recurrence, ROUND-11: r10 + dedicated P-stager wave.
//
// ROOT CAUSE found in rounds 4-10's invariant ~3000 cy/step: wave0's P
// prefetch (cold HBM, ~800 cy) was issued ~100 cy before the next poll,
// whose entry s_waitcnt vmcnt(0) DRAINED it — inserting ~800 cy of pure
// HBM latency into the serial publish->detect chain every step, in every
// design since r4. Fix: a 9th wave per WG stages P[t] slices into an LDS
// ring 2-3 steps ahead (throttled by wave0's existing monotonic wflag[0]);
// wave0 reads pv via LDS (lgkm only). Polling waves' vmem stream is now
// polls + publish store only (store-ack drain hides under visibility).
// Ring safety (depth 4): slot t&3 overwritten only when wflag[0] >= t-2,
// which implies step t-4 (and its P read) completed.
// ---------------------------------------------------------------------------
__global__ __launch_bounds__(RTHREADS, 2) void rnn_recur(
    const float* __restrict__ P,     // [SEQ][HSZ]  (Wx@x_t + bh)
    const float* __restrict__ Wh,    // [HSZ][HSZ]
    float* __restrict__ h_hist)      // [SEQ+1][HSZ]; row0=0, rows 1..=SENT
{
  const int g = blockIdx.x;
  const int tid = threadIdx.x;
  const int w = tid >> 6;          // wave 0..7 = compute, wave 8 = P stager
  const int l = tid & 63;
  const int g64 = g << 6;

  __shared__ float part[2][8][64];   // double-buffered partials
  __shared__ int   wflag[8];         // monotonic per-wave step counters
  __shared__ float pring[4][64];     // P slice ring (wave-8 -> wave-0)
  __shared__ int   ptag[4];          // monotonic row tags for pring
  if (tid < 8) wflag[tid] = 0;
  if (tid < 4) ptag[tid] = -1;
  __syncthreads();                   // prologue only

  if (w == 8) {
    // ---------------- P stager: off the critical path ----------------------
    for (int n = 0; n < SEQ; ++n) {
      // Throttle: stay <=2-3 rows ahead of wave0 (wflag[0] = steps done).
      while (__hip_atomic_load(&wflag[0], __ATOMIC_ACQUIRE,
                               __HIP_MEMORY_SCOPE_WORKGROUP) < n - 2) { }
      float v = P[(size_t)n * HSZ + g64 + l];   // HBM latency eaten HERE
      pring[n & 3][l] = v;
      // Release-tag after the whole wave's data writes (lgkm-ordered).
      if (l == 0)
        __hip_atomic_store(&ptag[n & 3], n, __ATOMIC_RELEASE,
                           __HIP_MEMORY_SCOPE_WORKGROUP);
    }
    return;
  }

  // ---------------- compute waves 0..7 (identical to r10) ------------------
  const int row = g64 + l;
  const int kbase = w << 6;

  // Lane's 64 weights, f16-packed: 32 half2 = 32 VGPRs.
  unsigned wreg[32];
  {
    const float2* ws = (const float2*)(Wh + (size_t)row * HSZ + kbase);
#pragma unroll
    for (int j = 0; j < 32; ++j) {
      float2 f = ws[j];
      unsigned u = pkrtz_u(f.x, f.y);
      asm("" : "+v"(u));
      wreg[j] = u;
    }
  }

  for (int t = 0; t < SEQ; ++t) {
    const int buf = t & 1;

    // 1) Poll own h chunk. Row 0 pre-zeroed. Only outstanding vmem at entry
    //    is (for wave0) the previous publish store — ack hides under fabric
    //    visibility, unlike the old P prefetch.
    float vh = poll_sent(h_hist + (size_t)t * HSZ + kbase + l, SENT);

    // 2) Pack h to f16 pairs.
    float vn = __shfl_xor(vh, 1);
    unsigned hpu = pkrtz_u(vh, vn);

    // 3) Dot: 32 readlane + 32 dot2, 4 accumulator chains.
    float a0 = 0.f, a1 = 0.f, a2 = 0.f, a3 = 0.f;
#pragma unroll
    for (int j = 0; j < 8; ++j) {
      a0 = dot2f(bch2(wreg[4 * j + 0]),
                 bch2(__builtin_amdgcn_readlane(hpu, 8 * j + 0)), a0);
      a1 = dot2f(bch2(wreg[4 * j + 1]),
                 bch2(__builtin_amdgcn_readlane(hpu, 8 * j + 2)), a1);
      a2 = dot2f(bch2(wreg[4 * j + 2]),
                 bch2(__builtin_amdgcn_readlane(hpu, 8 * j + 4)), a2);
      a3 = dot2f(bch2(wreg[4 * j + 3]),
                 bch2(__builtin_amdgcn_readlane(hpu, 8 * j + 6)), a3);
    }
    part[buf][w][l] = (a0 + a1) + (a2 + a3);

    // 4) Release-flag my partial (monotonic, no barrier).
    if (l == 0)
      __hip_atomic_store(&wflag[w], t + 1, __ATOMIC_RELEASE,
                         __HIP_MEMORY_SCOPE_WORKGROUP);

    if (w == 0) {
      // 5) Wait all 8 partials (lane-parallel spin).
      int fv;
      do {
        fv = __hip_atomic_load(&wflag[l & 7], __ATOMIC_ACQUIRE,
                               __HIP_MEMORY_SCOPE_WORKGROUP);
      } while (__any((int)(fv < t + 1)));
      // 6) Reduce partials + P (from the LDS ring; normally zero wait).
      float s = 0.f;
#pragma unroll
      for (int q = 0; q < 8; ++q) s += part[buf][q][l];
      while (__hip_atomic_load(&ptag[t & 3], __ATOMIC_ACQUIRE,
                               __HIP_MEMORY_SCOPE_WORKGROUP) < t) { }
      float xv = s + pring[t & 3][l];
      xv = fminf(fmaxf(xv, -15.f), 15.f);
      float e = __expf(2.f * xv);
      float hn = 1.f - 2.f / (e + 1.f);
      // 7) Publish: value IS the ready signal.
      __hip_atomic_store(&h_hist[(size_t)(t + 1) * HSZ + g64 + l], hn,
                         __ATOMIC_RELAXED, __HIP_MEMORY_SCOPE_AGENT);
    }
  }
}

// ---------------------------------------------------------------------------
extern "C" void kernel_launch(void* const* d_in, const int* in_sizes, int n_in,
                              void* d_out, int out_size, void* d_ws, size_t ws_size,
                              hipStream_t stream) {
  const float* x  = (const float*)d_in[0];  // [SEQ][ISZ]
  const float* Wx = (const float*)d_in[1];  // [HSZ][ISZ]
  const float* Wh = (const float*)d_in[2];  // [HSZ][HSZ]
  const float* Wy = (const float*)d_in[3];  // [OSZ][HSZ]
  const float* bh = (const float*)d_in[4];  // [HSZ]
  const float* by = (const float*)d_in[5];  // [OSZ]
  float* out = (float*)d_out;               // [SEQ][OSZ]

  float* P      = (float*)d_ws;             // SEQ*HSZ      (64 MB)
  float* h_hist = P + (size_t)SEQ * HSZ;    // (SEQ+1)*HSZ  (64 MB)

  // Sentinel-fill h_hist rows (NaN bits), then zero row 0 (= h_0).
  (void)hipMemsetD32Async((hipDeviceptr_t)h_hist, (int)SENT,
                          (size_t)(SEQ + 1) * HSZ, stream);
  (void)hipMemsetAsync(h_hist, 0, HSZ * sizeof(float), stream);

  // Phase 1: P = x @ Wx^T + bh
  gemm_bt_bias<<<dim3(SEQ / 64, HSZ / 64), dim3(256), 0, stream>>>(
      x, Wx, bh, P, SEQ, HSZ, ISZ);

  // Phase 2: sequential recurrence (8 persistent WGs, 9 waves each)
  rnn_recur<<<dim3(GWG), dim3(RTHREADS), 0, stream>>>(P, Wh, h_hist);

  // Phase 3: y = h_hist[1..] @ Wy^T + by
  gemm_bt_bias<<<dim3(SEQ / 64, OSZ / 64), dim3(256), 0, stream>>>(
      h_hist + HSZ, Wy, by, out, SEQ, OSZ, HSZ);
}

// Round 12
// 32023.132 us; speedup vs baseline: 1.2972x; 1.2972x over previous
//
#include <hip/hip_runtime.h>

#define SEQ 32768
#define ISZ 256
#define HSZ 512
#define OSZ 256
#define NLAUNCH 64       // 64 blocks; participants: blockIdx%8==0 (XCD round-robin heuristic)
#define RTHREADS 576     // waves 0..7 = consumers, wave 8 = producer
#define SENT 0x7FAAAAAAu // NaN sentinel for the slow (fabric) path
#define KFAST 8          // fast-poll iterations before falling back
#define LATCH_T 48       // fast-path verification window (steps)

typedef unsigned long long u64;
typedef _Float16 half2_t __attribute__((ext_vector_type(2)));

#if defined(__has_builtin)
#if __has_builtin(__builtin_amdgcn_fdot2)
#define HAVE_FDOT2 1
#endif
#endif

__device__ __forceinline__ float dot2f(half2_t a, half2_t b, float c) {
#ifdef HAVE_FDOT2
  return __builtin_amdgcn_fdot2(a, b, c, false);   // v_dot2_f32_f16
#else
  return fmaf((float)a.x, (float)b.x, fmaf((float)a.y, (float)b.y, c));
#endif
}
__device__ __forceinline__ half2_t bch2(unsigned u) {
  return __builtin_bit_cast(half2_t, u);
}
__device__ __forceinline__ unsigned pkrtz_u(float x, float y) {
  return __builtin_bit_cast(unsigned, __builtin_amdgcn_cvt_pkrtz(x, y));
}

// ---------------------------------------------------------------------------
// Generic tiled GEMM:  C[M,N] = A[M,K] @ W[N,K]^T + bias[N]
// ---------------------------------------------------------------------------
__global__ __launch_bounds__(256) void gemm_bt_bias(
    const float* __restrict__ A, const float* __restrict__ W,
    const float* __restrict__ bias, float* __restrict__ C,
    int M, int N, int K)
{
  __shared__ float As[32][68];
  __shared__ float Bs[32][68];
  const int tx = threadIdx.x;
  const int tn = tx & 15, tm = tx >> 4;
  const int m0 = blockIdx.x * 64, n0 = blockIdx.y * 64;
  const int kl = tx & 31;
  const int rl = tx >> 5;
  float acc[4][4] = {};

  for (int kt = 0; kt < K; kt += 32) {
#pragma unroll
    for (int i = 0; i < 8; ++i) {
      int m = rl + i * 8;
      As[kl][m] = A[(size_t)(m0 + m) * K + kt + kl];
      Bs[kl][m] = W[(size_t)(n0 + m) * K + kt + kl];
    }
    __syncthreads();
#pragma unroll
    for (int k = 0; k < 32; ++k) {
      float a[4], b[4];
#pragma unroll
      for (int i = 0; i < 4; ++i) a[i] = As[k][tm * 4 + i];
#pragma unroll
      for (int j = 0; j < 4; ++j) b[j] = Bs[k][tn * 4 + j];
#pragma unroll
      for (int i = 0; i < 4; ++i)
#pragma unroll
        for (int j = 0; j < 4; ++j)
          acc[i][j] = fmaf(a[i], b[j], acc[i][j]);
    }
    __syncthreads();
  }
#pragma unroll
  for (int i = 0; i < 4; ++i) {
    int m = m0 + tm * 4 + i;
#pragma unroll
    for (int j = 0; j < 4; ++j) {
      int n = n0 + tn * 4 + j;
      C[(size_t)m * N + n] = acc[i][j] + bias[n];
    }
  }
}

// Slow path (r10-proven): 2-deep pipelined sentinel poll, fabric-coherent.
__device__ __forceinline__ float poll_sent(const float* p, unsigned sent) {
  float a, b;
  asm volatile(
      "s_waitcnt vmcnt(0)\n\t"
      "global_load_dword %0, %2, off sc0 sc1\n\t"
      "global_load_dword %1, %2, off sc0 sc1\n"
      "1:\n\t"
      "s_waitcnt vmcnt(1)\n\t"
      "v_cmp_eq_u32 vcc, %3, %0\n\t"
      "s_cbranch_vccz 3f\n\t"
      "global_load_dword %0, %2, off sc0 sc1\n\t"
      "s_waitcnt vmcnt(1)\n\t"
      "v_cmp_eq_u32 vcc, %3, %1\n\t"
      "s_cbranch_vccz 2f\n\t"
      "global_load_dword %1, %2, off sc0 sc1\n\t"
      "s_branch 1b\n"
      "2:\n\t"
      "v_mov_b32 %0, %1\n"
      "3:\n\t"
      "s_waitcnt vmcnt(0)"
      : "=&v"(a), "=&v"(b)
      : "v"(p), "v"(sent)
      : "memory", "vcc");
  return a;
}

// Fast path: sc0-only (L1-bypass, L2-scope). Visible same-XCD; a different-XCD
// reader simply never sees it (bounded K + fallback => placement affects speed,
// never correctness).
__device__ __forceinline__ u64 load_fast(const u64* p) {
  u64 v;
  asm volatile("global_load_dwordx2 %0, %1, off sc0\n\t"
               "s_waitcnt vmcnt(0)"
               : "=v"(v) : "v"(p) : "memory");
  return v;
}
__device__ __forceinline__ void store_fast(u64* p, u64 v) {
  asm volatile("global_store_dwordx2 %0, %1, off sc0" :: "v"(p), "v"(v)
               : "memory");
}

// ---------------------------------------------------------------------------
// Persistent recurrence, ROUND-12: same-XCD fast ring + guaranteed fallback.
//
// Rounds 4-11: seven restructures (compute dtype, weights, barriers, P
// staging, poll depth) ALL land at 1.27us/step +-2% -> the serial chain is
// ~entirely the cross-XCD publish->visible->detect fabric RT (~3000cy); the
// 8 WGs round-robin onto 8 different XCDs. This round: participants are
// blocks {0,8,...,56} of a 64-block launch (same residue -> same XCD under
// the documented round-robin heuristic). Producer publishes h BOTH as
// tagged {step,val} u64s into a per-consumer fast ring (sc0 stores, L2) AND
// as the r10 sentinel h_hist row (sc1, fabric). Consumers: K=8 sc0 poll
// iters on the tagged ring, then fall back to the proven sentinel poll.
// use_fast latches off after a 48-step window if fast isn't hitting.
// Placement affects ONLY speed (G16): wrong mapping -> ~r10 perf, no hang.
// Tags (not sentinels) in the ring -> no reset races; slot reuse at t+4 is
// causally ordered via the dense coupling chain. Wave roles: 0..7 pure
// consumers (vmem = polls only; chunk g goes via LDS), wave 8 = producer
// (flags spin -> reduce -> tanh -> dual publish -> P prefetch).
// ---------------------------------------------------------------------------
__global__ __launch_bounds__(RTHREADS, 2) void rnn_recur(
    const float* __restrict__ P,     // [SEQ][HSZ]
    const float* __restrict__ Wh,    // [HSZ][HSZ]
    float* __restrict__ h_hist,      // [SEQ+1][HSZ]; row0=0, rows 1..=SENT
    u64* __restrict__ fring)         // [8 consumerWG][4 slot][8 chunk][64], tags=0
{
  const int b = blockIdx.x;
  if (b & 7) return;                 // participants: one block per XCD-residue 0
  const int g = b >> 3;              // participant id 0..7
  const int tid = threadIdx.x;
  const int w = tid >> 6;            // 0..7 consumers, 8 producer
  const int l = tid & 63;
  const int g64 = g << 6;

  __shared__ float part[2][8][64];   // partials, double-buffered by t&1
  __shared__ float hown[2][64];      // own chunk g of h, for wave g (LDS hop)
  __shared__ int   wflag[8];         // monotonic per-consumer step counters
  __shared__ int   hofl;             // monotonic: hown publication counter
  if (tid < 8) wflag[tid] = 0;
  if (tid == 8) hofl = 0;
  __syncthreads();                   // prologue only

  if (w == 8) {
    // ------------------------------ producer -------------------------------
    float pv = P[g64 + l];           // P[0]
    for (int t = 0; t < SEQ; ++t) {
      const int buf = t & 1;
      int fv;
      do {
        fv = __hip_atomic_load(&wflag[l & 7], __ATOMIC_ACQUIRE,
                               __HIP_MEMORY_SCOPE_WORKGROUP);
      } while (__any((int)(fv < t + 1)));
      float s = 0.f;
#pragma unroll
      for (int q = 0; q < 8; ++q) s += part[buf][q][l];
      float xv = s + pv;
      xv = fminf(fmaxf(xv, -15.f), 15.f);
      float e = __expf(2.f * xv);
      float hn = 1.f - 2.f / (e + 1.f);
      // Slow-path + final-output publish (fabric; value IS the signal).
      __hip_atomic_store(&h_hist[(size_t)(t + 1) * HSZ + g64 + l], hn,
                         __ATOMIC_RELAXED, __HIP_MEMORY_SCOPE_AGENT);
      // Fast-path publish: tagged copies, one per consumer WG (sc0 -> L2).
      const u64 pk = ((u64)(unsigned)(t + 1) << 32) | (u64)__float_as_uint(hn);
      const int slot = (t + 1) & 3;
#pragma unroll
      for (int j = 0; j < 8; ++j)
        store_fast(fring + (((size_t)j * 4 + slot) * 8 + g) * 64 + l, pk);
      // Intra-WG hop via LDS for our own wave g.
      hown[(t + 1) & 1][l] = hn;
      if (l == 0)
        __hip_atomic_store(&hofl, t + 1, __ATOMIC_RELEASE,
                           __HIP_MEMORY_SCOPE_WORKGROUP);
      // P prefetch: full step to arrive; drained behind next flag spin.
      pv = P[(size_t)(t + 1 < SEQ ? t + 1 : SEQ - 1) * HSZ + g64 + l];
    }
    return;
  }

  // ------------------------------ consumers --------------------------------
  const int row = g64 + l;
  const int kbase = w << 6;

  // Lane's 64 weights, f16-packed: 32 half2 regs (r10-proven dot).
  unsigned wreg[32];
  {
    const float2* ws = (const float2*)(Wh + (size_t)row * HSZ + kbase);
#pragma unroll
    for (int j = 0; j < 32; ++j) {
      float2 f = ws[j];
      unsigned u = pkrtz_u(f.x, f.y);
      asm("" : "+v"(u));
      wreg[j] = u;
    }
  }

  const bool lds_path = (w == g);
  int fastok = 0;
  int use_fast = 1;

  for (int t = 0; t < SEQ; ++t) {
    float vh = 0.f;
    if (t > 0) {
      if (lds_path) {
        while (__hip_atomic_load(&hofl, __ATOMIC_ACQUIRE,
                                 __HIP_MEMORY_SCOPE_WORKGROUP) < t) { }
        vh = hown[t & 1][l];
      } else {
        int got = 0;
        if (use_fast) {
          const u64* fp = fring + (((size_t)g * 4 + (t & 3)) * 8 + w) * 64 + l;
          for (int k = 0; k < KFAST; ++k) {
            u64 v = load_fast(fp);
            if (__all((int)((unsigned)(v >> 32) == (unsigned)t))) {
              vh = __uint_as_float((unsigned)v);
              got = 1;
              break;
            }
          }
          if (t <= LATCH_T) {
            fastok += got;
            if (t == LATCH_T && fastok < LATCH_T - 8) use_fast = 0;
          }
        }
        if (!got)
          vh = poll_sent(h_hist + (size_t)t * HSZ + kbase + l, SENT);
      }
    }

    // Pack h to f16 pairs; 32 readlane + 32 dot2, 4 accumulator chains.
    float vn = __shfl_xor(vh, 1);
    unsigned hpu = pkrtz_u(vh, vn);
    float a0 = 0.f, a1 = 0.f, a2 = 0.f, a3 = 0.f;
#pragma unroll
    for (int j = 0; j < 8; ++j) {
      a0 = dot2f(bch2(wreg[4 * j + 0]),
                 bch2(__builtin_amdgcn_readlane(hpu, 8 * j + 0)), a0);
      a1 = dot2f(bch2(wreg[4 * j + 1]),
                 bch2(__builtin_amdgcn_readlane(hpu, 8 * j + 2)), a1);
      a2 = dot2f(bch2(wreg[4 * j + 2]),
                 bch2(__builtin_amdgcn_readlane(hpu, 8 * j + 4)), a2);
      a3 = dot2f(bch2(wreg[4 * j + 3]),
                 bch2(__builtin_amdgcn_readlane(hpu, 8 * j + 6)), a3);
    }
    part[t & 1][w][l] = (a0 + a1) + (a2 + a3);
    if (l == 0)
      __hip_atomic_store(&wflag[w], t + 1, __ATOMIC_RELEASE,
                         __HIP_MEMORY_SCOPE_WORKGROUP);
  }
}

// ---------------------------------------------------------------------------
extern "C" void kernel_launch(void* const* d_in, const int* in_sizes, int n_in,
                              void* d_out, int out_size, void* d_ws, size_t ws_size,
                              hipStream_t stream) {
  const float* x  = (const float*)d_in[0];  // [SEQ][ISZ]
  const float* Wx = (const float*)d_in[1];  // [HSZ][ISZ]
  const float* Wh = (const float*)d_in[2];  // [HSZ][HSZ]
  const float* Wy = (const float*)d_in[3];  // [OSZ][HSZ]
  const float* bh = (const float*)d_in[4];  // [HSZ]
  const float* by = (const float*)d_in[5];  // [OSZ]
  float* out = (float*)d_out;               // [SEQ][OSZ]

  float* P      = (float*)d_ws;             // SEQ*HSZ      (64 MB)
  float* h_hist = P + (size_t)SEQ * HSZ;    // (SEQ+1)*HSZ  (64 MB)
  u64*   fring  = (u64*)(h_hist + (size_t)(SEQ + 1) * HSZ); // 128 KB

  // Sentinel-fill h_hist (slow path), zero row 0; zero fring tags.
  (void)hipMemsetD32Async((hipDeviceptr_t)h_hist, (int)SENT,
                          (size_t)(SEQ + 1) * HSZ, stream);
  (void)hipMemsetAsync(h_hist, 0, HSZ * sizeof(float), stream);
  (void)hipMemsetAsync(fring, 0, (size_t)8 * 4 * 8 * 64 * sizeof(u64), stream);

  // Phase 1: P = x @ Wx^T + bh
  gemm_bt_bias<<<dim3(SEQ / 64, HSZ / 64), dim3(256), 0, stream>>>(
      x, Wx, bh, P, SEQ, HSZ, ISZ);

  // Phase 2: recurrence (8 participants selected by XCD-residue heuristic)
  rnn_recur<<<dim3(NLAUNCH), dim3(RTHREADS), 0, stream>>>(P, Wh, h_hist, fring);

  // Phase 3: y = h_hist[1..] @ Wy^T + by
  gemm_bt_bias<<<dim3(SEQ / 64, OSZ / 64), dim3(256), 0, stream>>>(
      h_hist + HSZ, Wy, by, out, SEQ, OSZ, HSZ);
}